// Round 1
// 394.149 us; speedup vs baseline: 1.0566x; 1.0566x over previous
//
#include <hip/hip_runtime.h>
#include <hip/hip_bf16.h>
#include <math.h>

typedef __bf16 bf16;
typedef __bf16 bf16x8 __attribute__((ext_vector_type(8)));
typedef float floatx4 __attribute__((ext_vector_type(4)));

#define GAS __attribute__((address_space(1)))
#define LAS __attribute__((address_space(3)))

static constexpr int B_ = 16, L_ = 4096, C_ = 512;
static constexpr int M_ = B_ * L_;   // 65536 rows (b,l)
static constexpr int K_ = 3 * C_;    // 1536

// ---- K1: fused prep. blocks [0,16384): cast x f32->bf16; [16384,19456): repack w_down.
__global__ void prep(const float* __restrict__ x, bf16* __restrict__ xb,
                     const float* __restrict__ wd, bf16* __restrict__ wr) {
    if (blockIdx.x < 16384) {
        const size_t i = ((size_t)blockIdx.x * 256 + threadIdx.x) * 8;
        floatx4 a = *(const floatx4*)(x + i);
        floatx4 b = *(const floatx4*)(x + i + 4);
        bf16x8 o;
#pragma unroll
        for (int j = 0; j < 4; ++j) { o[j] = (bf16)a[j]; o[4 + j] = (bf16)b[j]; }
        *(bf16x8*)(xb + i) = o;
    } else {
        int idx = (blockIdx.x - 16384) * 256 + threadIdx.x;   // 512*1536 total
        int o   = idx / K_;
        int rem = idx - o * K_;
        int kk  = rem >> 9;
        int i   = rem & 511;
        wr[idx] = (bf16)wd[o * K_ + i * 3 + kk];
    }
}

// ---- K2: dilated-conv-as-GEMM, 256x256 tile, BK=64, double-buffered LDS with
// COUNTED vmcnt (T3+T4) + setprio (T5) + XOR swizzle (T2).
// Old structure: STAGE; syncthreads; compute; syncthreads  -> every K-step drains
// vmcnt(0) (MfmaUtil 31%). New: per tile kt: compute(buf) ; s_barrier ;
// STAGE(kt+2 -> buf) ; s_waitcnt vmcnt(8)  [= only tile kt+1's loads must land,
// the 8 just-issued stay in flight across the barrier] ; s_barrier.
// 8 waves = 2(M) x 4(N), per-wave C = 128x64 -> acc[8][4] (128 VGPR).
__global__ __launch_bounds__(512, 2) void gemm_conv(
    const bf16* __restrict__ x, const bf16* __restrict__ wr,
    const float* __restrict__ bd, bf16* __restrict__ xp, float* __restrict__ sums)
{
    __shared__ bf16 As[2 * 256 * 64];   // 64 KB (2 buffers)
    __shared__ bf16 Bs[2 * 256 * 64];   // 64 KB

    const int tid = threadIdx.x;
    // XCD swizzle: the 2 n-blocks of one m-tile land on the same XCD.
    const int u   = blockIdx.x;           // 0..511
    const int mb  = (u & 7) + 8 * (u >> 4);
    const int nb  = (u >> 3) & 1;
    const int m0  = mb * 256;
    const int n0  = nb * 256;

    const int wave = tid >> 6;
    const int lane = tid & 63;
    const int wm = wave & 1;              // 2 m-strips of 128
    const int wn = wave >> 1;             // 4 n-strips of 64
    const int tm = lane & 15;
    const int quad = lane >> 4;

    floatx4 acc[8][4];
#pragma unroll
    for (int i = 0; i < 8; ++i)
#pragma unroll
        for (int j = 0; j < 4; ++j) acc[i][j] = floatx4{0.f, 0.f, 0.f, 0.f};

    // staging map: chunk qa = tid + 512j (16B each); row = qa>>3, landing chunk p = qa&7,
    // SOURCE chunk = p ^ (row&7)  (XOR swizzle; reads recompute the same XOR)
    int srow[4], ssc[4];
#pragma unroll
    for (int j = 0; j < 4; ++j) {
        const int qa = tid + 512 * j;
        srow[j] = qa >> 3;
        ssc[j]  = (qa & 7) ^ (srow[j] & 7);
    }

    // read-side swizzled chunk offsets (elems), k-half 0/1; rows == tm (mod 8) always
    const int xo0 = (quad ^ (tm & 7)) << 3;
    const int xo1 = ((4 + quad) ^ (tm & 7)) << 3;
    int aoff[8], boff[4];
#pragma unroll
    for (int mi = 0; mi < 8; ++mi) aoff[mi] = (wm * 128 + mi * 16 + tm) * 64;
#pragma unroll
    for (int ni = 0; ni < 4; ++ni) boff[ni] = (wn * 64 + ni * 16 + tm) * 64;

    auto stage = [&](int t, int b) {
        const int kk = t >> 3;            // tap 0..2
        const int i0 = (t & 7) << 6;      // input-channel base 0..448
        bf16* Ad = As + b * (256 * 64);
        bf16* Bd = Bs + b * (256 * 64);
#pragma unroll
        for (int j = 0; j < 4; ++j) {
            int sr = m0 + srow[j] + 2 * kk; if (sr > M_ - 1) sr = M_ - 1;
            const bf16* sa = x + (size_t)sr * C_ + i0 + ssc[j] * 8;
            __builtin_amdgcn_global_load_lds((const GAS void*)sa,
                (LAS void*)(Ad + (tid + 512 * j) * 8), 16, 0, 0);
            const bf16* sb = wr + (size_t)(n0 + srow[j]) * K_ + kk * C_ + i0 + ssc[j] * 8;
            __builtin_amdgcn_global_load_lds((const GAS void*)sb,
                (LAS void*)(Bd + (tid + 512 * j) * 8), 16, 0, 0);
        }
    };

    auto compute = [&](const bf16* Ab, const bf16* Bb) {
        bf16x8 bfr[2][4];
#pragma unroll
        for (int kh = 0; kh < 2; ++kh)
#pragma unroll
            for (int ni = 0; ni < 4; ++ni)
                bfr[kh][ni] = *(const bf16x8*)(Bb + boff[ni] + (kh ? xo1 : xo0));
#pragma unroll
        for (int mq = 0; mq < 2; ++mq) {
            bf16x8 afr[2][4];
#pragma unroll
            for (int kh = 0; kh < 2; ++kh)
#pragma unroll
                for (int mi = 0; mi < 4; ++mi)
                    afr[kh][mi] = *(const bf16x8*)(Ab + aoff[mq * 4 + mi] + (kh ? xo1 : xo0));
            __builtin_amdgcn_s_setprio(1);
#pragma unroll
            for (int kh = 0; kh < 2; ++kh)
#pragma unroll
                for (int mi = 0; mi < 4; ++mi)
#pragma unroll
                    for (int ni = 0; ni < 4; ++ni)
                        acc[mq * 4 + mi][ni] = __builtin_amdgcn_mfma_f32_16x16x32_bf16(
                            afr[kh][mi], bfr[kh][ni], acc[mq * 4 + mi][ni], 0, 0, 0);
            __builtin_amdgcn_s_setprio(0);
        }
    };

    // prologue: tiles 0 (buf0) and 1 (buf1) in flight; wait only for tile 0.
    stage(0, 0);
    stage(1, 1);
    asm volatile("s_waitcnt vmcnt(8)" ::: "memory");
    asm volatile("s_barrier" ::: "memory");

    // main loop: tiles 0..21 (stage reaches tile 23). vmcnt(8) = counted, never 0.
    for (int kt2 = 0; kt2 < 22; kt2 += 2) {
        compute(As, Bs);
        asm volatile("s_barrier" ::: "memory");        // all reads of buf0 done
        stage(kt2 + 2, 0);
        asm volatile("s_waitcnt vmcnt(8)" ::: "memory"); // tile kt2+1 landed
        asm volatile("s_barrier" ::: "memory");

        compute(As + 256 * 64, Bs + 256 * 64);
        asm volatile("s_barrier" ::: "memory");        // all reads of buf1 done
        stage(kt2 + 3, 1);
        asm volatile("s_waitcnt vmcnt(8)" ::: "memory"); // tile kt2+2 landed
        asm volatile("s_barrier" ::: "memory");
    }
    // tail: tiles 22 (buf0) and 23 (buf1); single full drain at the very end.
    compute(As, Bs);
    asm volatile("s_barrier" ::: "memory");
    asm volatile("s_waitcnt vmcnt(0)" ::: "memory");   // tile 23 landed
    asm volatile("s_barrier" ::: "memory");
    compute(As + 256 * 64, Bs + 256 * 64);

    // epilogue: + bias, store bf16, fused stats. C/D: col=lane&15, row=quad*4+reg.
    float bias[4];
#pragma unroll
    for (int ni = 0; ni < 4; ++ni) bias[ni] = bd[n0 + wn * 64 + ni * 16 + tm];

    float s[4] = {0, 0, 0, 0}, q[4] = {0, 0, 0, 0};
#pragma unroll
    for (int mi = 0; mi < 8; ++mi) {
#pragma unroll
        for (int r = 0; r < 4; ++r) {
            const int m = m0 + wm * 128 + mi * 16 + quad * 4 + r;
            const bool valid = (m & (L_ - 1)) < L_ - 4;   // exclude garbage boundary rows
            bf16* dst = xp + (size_t)m * C_ + n0 + wn * 64 + tm;
#pragma unroll
            for (int ni = 0; ni < 4; ++ni) {
                const float v = acc[mi][ni][r] + bias[ni];
                dst[ni * 16] = (bf16)v;
                if (valid) { s[ni] += v; q[ni] += v * v; }
            }
        }
    }
#pragma unroll
    for (int ni = 0; ni < 4; ++ni) {
        float sv = s[ni], qv = q[ni];
        sv += __shfl_xor(sv, 16); sv += __shfl_xor(sv, 32);
        qv += __shfl_xor(qv, 16); qv += __shfl_xor(qv, 32);
        if (quad == 0) {
            const int c = n0 + wn * 64 + ni * 16 + tm;
            atomicAdd(&sums[c], sv);
            atomicAdd(&sums[C_ + c], qv);
        }
    }
}

// ---- K3: boundary rows l in [4092,4096): xp = w_pad . x + b_pad, plus their stats
__global__ void fixup(const float* __restrict__ x, const float* __restrict__ wp,
                      const float* __restrict__ bp, bf16* __restrict__ xp,
                      float* __restrict__ sums)
{
    const int b = blockIdx.x >> 2;
    const int j = blockIdx.x & 3;
    __shared__ float xrow[C_];
    for (int i = threadIdx.x; i < C_; i += 256)
        xrow[i] = x[(size_t)(b * L_ + j) * C_ + i];
    __syncthreads();
    for (int c = threadIdx.x; c < C_; c += 256) {
        const float* w = wp + (size_t)c * C_;
        float acc = 0.f;
#pragma unroll 4
        for (int i = 0; i < C_; i += 4) {
            floatx4 wv = *(const floatx4*)(w + i);
#pragma unroll
            for (int u = 0; u < 4; ++u) acc += wv[u] * xrow[i + u];
        }
        const float v = acc + bp[c];
        xp[(size_t)(b * L_ + 4092 + j) * C_ + c] = (bf16)v;
        atomicAdd(&sums[c], v);
        atomicAdd(&sums[C_ + c], v * v);
    }
}

// ---- K4: BN(from raw sums) -> ELU -> +residual(bf16) -> maxpool(3,2,pad1) -> [B,L/2,C] f32
__global__ void final_pool(const bf16* __restrict__ xp, const bf16* __restrict__ xb,
                           const float* __restrict__ sums, const float* __restrict__ gamma,
                           const float* __restrict__ beta, float* __restrict__ out)
{
    const int gid = blockIdx.x * 256 + threadIdx.x;  // B * 2048 * 64 groups of 8 ch
    const int cg = gid & 63;
    const int t  = (gid >> 6) & 2047;
    const int b  = gid >> 17;
    const int c0 = cg << 3;

    float sc[8], sh[8];
    const float invn = 1.0f / 65536.0f;
#pragma unroll
    for (int j = 0; j < 8; ++j) {
        const int c = c0 + j;
        float mean = sums[c] * invn;
        float var  = sums[C_ + c] * invn - mean * mean;
        float scale = gamma[c] * rsqrtf(var + 1e-5f);
        sc[j] = scale;
        sh[j] = beta[c] - mean * scale;
    }

    float best[8];
#pragma unroll
    for (int j = 0; j < 8; ++j) best[j] = -INFINITY;

#pragma unroll
    for (int dl = -1; dl <= 1; ++dl) {
        const int l = 2 * t + dl;
        if (l < 0) continue;                        // right edge never exceeds 4095
        const size_t off = (size_t)(b * L_ + l) * C_ + c0;
        bf16x8 xpv = *(const bf16x8*)(xp + off);
        bf16x8 xv  = *(const bf16x8*)(xb + off);
#pragma unroll
        for (int j = 0; j < 8; ++j) {
            float z = sc[j] * (float)xpv[j] + sh[j];
            float y = (z > 0.f) ? z : (__expf(z) - 1.f);
            y += (float)xv[j];
            best[j] = fmaxf(best[j], y);
        }
    }
    floatx4 o0, o1;
#pragma unroll
    for (int j = 0; j < 4; ++j) { o0[j] = best[j]; o1[j] = best[4 + j]; }
    *(floatx4*)(out + (size_t)gid * 8) = o0;
    *(floatx4*)(out + (size_t)gid * 8 + 4) = o1;
}

extern "C" void kernel_launch(void* const* d_in, const int* in_sizes, int n_in,
                              void* d_out, int out_size, void* d_ws, size_t ws_size,
                              hipStream_t stream)
{
    const float* x      = (const float*)d_in[0];
    const float* w_down = (const float*)d_in[1];
    const float* b_down = (const float*)d_in[2];
    const float* w_pad  = (const float*)d_in[3];
    const float* b_pad  = (const float*)d_in[4];
    const float* gamma  = (const float*)d_in[5];
    const float* beta   = (const float*)d_in[6];
    float* out = (float*)d_out;

    char* ws = (char*)d_ws;
    bf16*  xb   = (bf16*)ws;                                        // 64 MiB  [B*L][C] bf16 copy of x
    bf16*  xp   = (bf16*)(ws + (size_t)M_ * C_ * 2);                // 64 MiB  [B*L][C]
    bf16*  wr   = (bf16*)(ws + (size_t)M_ * C_ * 4);                // 1.5 MiB [O][K]
    float* sums = (float*)(ws + (size_t)M_ * C_ * 4 + (size_t)C_ * K_ * 2);  // 1024 f32

    hipMemsetAsync(sums, 0, 2 * C_ * sizeof(float), stream);
    prep<<<dim3(16384 + 3072), dim3(256), 0, stream>>>(x, xb, w_down, wr);
    gemm_conv<<<dim3(512), dim3(512), 0, stream>>>(xb, wr, b_down, xp, sums);
    fixup<<<dim3(64), dim3(256), 0, stream>>>(x, w_pad, b_pad, xp, sums);
    final_pool<<<dim3(8192), dim3(256), 0, stream>>>(xp, xb, sums, gamma, beta, out);
}